// Round 3
// baseline (58.402 us; speedup 1.0000x reference)
//
#include <hip/hip_runtime.h>
#include <hip/hip_bf16.h>

typedef __attribute__((ext_vector_type(4))) float f32x4;
typedef __attribute__((ext_vector_type(4))) short s16x4;
typedef __attribute__((ext_vector_type(8))) short s16x8;

#define NB 8
#define NC 16
#define HH 512
#define WW 512
// l = Hp*64 + Wp (4096), l' = hp*8 + wp (64), m = c*64 + kh*8 + kw (1024)

// ---------------- K1: 8x8 avg-pool -> B^T bf16 [b][m][l'] ----------------
__global__ __launch_bounds__(256) void pool_to_bt(const float* __restrict__ x,
                                                  __hip_bfloat16* __restrict__ bt) {
    int flat = blockIdx.x * 256 + threadIdx.x;      // 8*16*64*64 = 524288
    int wq = flat & 63;                             // pooled col w' (lane-consecutive -> coalesced)
    int hq = (flat >> 6) & 63;                      // pooled row h'
    int c  = (flat >> 12) & 15;
    int b  = flat >> 16;
    const float* base = x + ((size_t)(b * NC + c) * HH + hq * 8) * WW + wq * 8;
    float s = 0.f;
#pragma unroll
    for (int r = 0; r < 8; ++r) {
        f32x4 v0 = __builtin_nontemporal_load((const f32x4*)(base + (size_t)r * WW));
        f32x4 v1 = __builtin_nontemporal_load((const f32x4*)(base + (size_t)r * WW + 4));
        s += v0[0] + v0[1] + v0[2] + v0[3] + v1[0] + v1[1] + v1[2] + v1[3];
    }
    s *= (1.f / 64.f);
    int m  = c * 64 + (hq & 7) * 8 + (wq & 7);      // (c, kh, kw)
    int lp = (hq >> 3) * 8 + (wq >> 3);             // (hp, wp)
    bt[((size_t)b * 1024 + m) * 64 + lp] = __float2bfloat16(s);
}

// ------------- K2: Out[l,m] = attn_norm[l,:] * Bt[m,:], fold-scatter -------------
// MFMA operand roles: A-operand rows = m (from Bs), B-operand rows = l (from As).
// => D col (lane&15) indexes l, D row ((lane>>4)*4+r) indexes m. Per-thread acc
// regs run along m => along kw => f32x4 store of 4 consecutive output floats.
#define BM 128   // l per block
#define BN 128   // m per block
#define LDK 72   // 64 + 8 bf16 pad (144B pitch, 16B aligned)

__global__ __launch_bounds__(256) void gemm_scatter(const float* __restrict__ attn,
                                                    const __hip_bfloat16* __restrict__ bt,
                                                    float* __restrict__ out) {
    // 1D grid decode: sharers of one attn tile (same lb,b; mb 0..7) are
    // congruent mod 256 => same XCD residue under round-robin dispatch.
    int bi = blockIdx.x;
    int mb = bi >> 8;          // 0..7   m-tile
    int lb = (bi >> 3) & 31;   // 0..31  l-tile
    int b  = bi & 7;           // 0..7

    __shared__ __align__(16) unsigned short As[BM][LDK];   // attn_norm bf16 [l][k]
    __shared__ __align__(16) unsigned short Bs[BN][LDK];   // bt bf16        [m][k]

    int tid = threadIdx.x;

    // --- stage A: raw f32 attn -> normalize -> bf16 LDS (coalesced; 16 lanes/row) ---
    {
        const float* Abase = attn + ((size_t)(b * 4096 + lb * BM)) * 64;
#pragma unroll
        for (int i = 0; i < 8; ++i) {
            int cid   = tid + i * 256;         // 0..2047 chunks of 16B
            int chunk = cid & 15;              // 4 floats within the 64-float row
            int row   = cid >> 4;              // 0..127
            f32x4 v = *(const f32x4*)(Abase + (size_t)row * 64 + chunk * 4);
            int cnt = (v[0] != 0.f) + (v[1] != 0.f) + (v[2] != 0.f) + (v[3] != 0.f);
            cnt += __shfl_xor(cnt, 1);
            cnt += __shfl_xor(cnt, 2);
            cnt += __shfl_xor(cnt, 4);
            cnt += __shfl_xor(cnt, 8);         // row count across its 16 owner lanes
            float inv = 1.0f / ((float)cnt + 1e-5f);
            s16x4 o;
#pragma unroll
            for (int e = 0; e < 4; ++e) {
                __hip_bfloat16 h = __float2bfloat16(v[e] * inv);
                o[e] = (short)*reinterpret_cast<unsigned short*>(&h);
            }
            *(s16x4*)&As[row][chunk * 4] = o;
        }
    }
    // --- stage B: bt tile, coalesced 16B chunks ---
    {
        const unsigned short* Bg = (const unsigned short*)bt + ((size_t)b * 1024 + mb * BN) * 64;
#pragma unroll
        for (int i = 0; i < 4; ++i) {
            int cid = tid + i * 256;
            int row = cid >> 3, c8 = cid & 7;
            *(s16x8*)&Bs[row][c8 * 8] = *(const s16x8*)(Bg + row * 64 + c8 * 8);
        }
    }
    __syncthreads();

    int w    = tid >> 6;
    int lane = tid & 63;
    int wm   = (w & 1) * 64;      // wave m-base in tile
    int wl   = (w >> 1) * 64;     // wave l-base in tile
    int lr   = lane & 15;
    int kq   = lane >> 4;

    f32x4 acc[4][4] = {};         // [mi][lj]
#pragma unroll
    for (int ks = 0; ks < 2; ++ks) {                // K = 64 = 2 x 32
        s16x8 mf[4], lf[4];
#pragma unroll
        for (int i = 0; i < 4; ++i)
            mf[i] = *(const s16x8*)&Bs[wm + i * 16 + lr][ks * 32 + kq * 8];
#pragma unroll
        for (int j = 0; j < 4; ++j)
            lf[j] = *(const s16x8*)&As[wl + j * 16 + lr][ks * 32 + kq * 8];
#pragma unroll
        for (int i = 0; i < 4; ++i)
#pragma unroll
            for (int j = 0; j < 4; ++j)
                acc[i][j] = __builtin_amdgcn_mfma_f32_16x16x32_bf16(mf[i], lf[j], acc[i][j], 0, 0, 0);
    }

    // --- epilogue: nontemporal f32x4 stores; 4 consecutive m == 4 consecutive kw ---
#pragma unroll
    for (int mi = 0; mi < 4; ++mi) {
        int m0 = mb * BN + wm + mi * 16 + kq * 4;   // multiple of 4
        int c  = m0 >> 6, kh = (m0 >> 3) & 7, kw = m0 & 7;   // kw in {0,4}
        float* obase = out + (((size_t)(b * NC + c) * HH) + kh) * WW + kw;
#pragma unroll
        for (int lj = 0; lj < 4; ++lj) {
            int l  = lb * BM + wl + lj * 16 + lr;
            int Hp = l >> 6, Wp = l & 63;
            __builtin_nontemporal_store(acc[mi][lj],
                                        (f32x4*)(obase + ((size_t)Hp * 8) * WW + Wp * 8));
        }
    }
}

extern "C" void kernel_launch(void* const* d_in, const int* in_sizes, int n_in,
                              void* d_out, int out_size, void* d_ws, size_t ws_size,
                              hipStream_t stream) {
    const float* x    = (const float*)d_in[0];
    const float* attn = (const float*)d_in[1];
    float* out        = (float*)d_out;

    __hip_bfloat16* bt = (__hip_bfloat16*)d_ws;     // 1 MB: [8][1024][64]

    pool_to_bt<<<2048, 256, 0, stream>>>(x, bt);
    gemm_scatter<<<2048, 256, 0, stream>>>(attn, bt, out);
}